// Round 1
// baseline (512.772 us; speedup 1.0000x reference)
//
#include <hip/hip_runtime.h>

// AAF loss on MI355X. N=2, C=19, preds 64x64 -> bilinear(align_corners) 512x512,
// softmax over C, 8-neighbor binary-KL edge/non-edge loss, masked means, *0.01.

#define NC 19
#define HH 512
#define WW 512
#define NB 2
#define NPIX (NB * HH * WW)        // 524288
#define PROB_FLOATS ((size_t)NPIX * NC)

struct Accum {
    double e_sum, ne_sum;
    unsigned long long e_cnt, ne_cnt;
    float w_e[NC], w_ne[NC];
};

// ---------------- init: zero accumulators + class-weight softmax ----------------
__global__ void k_init(const float* __restrict__ w_edge,
                       const float* __restrict__ w_not_edge,
                       Accum* acc) {
    int t = threadIdx.x;
    if (t == 0) {
        acc->e_sum = 0.0; acc->ne_sum = 0.0;
        acc->e_cnt = 0ull; acc->ne_cnt = 0ull;
    }
    if (t < NC) {
        {
            float a = w_edge[t * 3 + 0], b = w_edge[t * 3 + 1], c = w_edge[t * 3 + 2];
            float m = fmaxf(a, fmaxf(b, c));
            float ea = __expf(a - m), eb = __expf(b - m), ec = __expf(c - m);
            acc->w_e[t] = ea / (ea + eb + ec);
        }
        {
            float a = w_not_edge[t * 3 + 0], b = w_not_edge[t * 3 + 1], c = w_not_edge[t * 3 + 2];
            float m = fmaxf(a, fmaxf(b, c));
            float ea = __expf(a - m), eb = __expf(b - m), ec = __expf(c - m);
            acc->w_ne[t] = ea / (ea + eb + ec);
        }
    }
}

// ---------------- prob: bilinear resize + softmax, NHWC fp32 into ws ----------------
__global__ __launch_bounds__(256) void k_prob(const float* __restrict__ preds,
                                              float* __restrict__ prob) {
    __shared__ float tile[256 * NC];
    const int tid = threadIdx.x;
    const int pix = blockIdx.x * 256 + tid;       // 0 .. NPIX-1
    const int n = pix >> 18;
    const int rem = pix & 0x3FFFF;
    const int y = rem >> 9;
    const int x = rem & 511;

    // align_corners mapping 512 -> 64: src = i * 63 / 511
    const float fy = (float)(y * 63) / 511.0f;
    const float fx = (float)(x * 63) / 511.0f;
    const int y0 = (int)fy;
    const int x0 = (int)fx;
    const float wy = fy - (float)y0;
    const float wx = fx - (float)x0;
    const int y1 = min(y0 + 1, 63);
    const int x1 = min(x0 + 1, 63);
    const float omwy = 1.0f - wy, omwx = 1.0f - wx;

    const float* pb = preds + (size_t)n * NC * 4096;
    float v[NC];
    float m = -1e30f;
#pragma unroll
    for (int c = 0; c < NC; ++c) {
        const float* pc_ = pb + c * 4096;
        const float p00 = pc_[(y0 << 6) + x0];
        const float p10 = pc_[(y1 << 6) + x0];
        const float p01 = pc_[(y0 << 6) + x1];
        const float p11 = pc_[(y1 << 6) + x1];
        // rows-then-cols order to match reference
        const float a = p00 * omwy + p10 * wy;
        const float b = p01 * omwy + p11 * wy;
        const float vv = a * omwx + b * wx;
        v[c] = vv;
        m = fmaxf(m, vv);
    }
    float s = 0.0f;
#pragma unroll
    for (int c = 0; c < NC; ++c) { v[c] = __expf(v[c] - m); s += v[c]; }
    const float inv = 1.0f / s;
#pragma unroll
    for (int c = 0; c < NC; ++c) tile[tid * NC + c] = v[c] * inv;

    __syncthreads();
    // coalesced store: block covers a contiguous span of 256*NC floats
    float* dst = prob + (size_t)blockIdx.x * (256 * NC);
    for (int i = tid; i < 256 * NC; i += 256) dst[i] = tile[i];
}

// ---------------- main loss kernel ----------------
__global__ __launch_bounds__(256) void k_main(const int* __restrict__ targets,
                                              const float* __restrict__ prob,
                                              Accum* acc) {
    __shared__ float swe[NC], swn[NC];
    const int tid = threadIdx.x;
    if (tid < NC) { swe[tid] = acc->w_e[tid]; swn[tid] = acc->w_ne[tid]; }
    __syncthreads();

    const int pix = blockIdx.x * 256 + tid;
    const int n = pix >> 18;
    const int rem = pix & 0x3FFFF;
    const int y = rem >> 9;
    const int x = rem & 511;

    const int* tg = targets + (n << 18);
    const int lab = tg[(y << 9) + x];

    float e_s = 0.0f, ne_s = 0.0f;
    int e_c = 0, ne_c = 0;

    if (lab <= NC - 1) {   // ignore_c = label > 18 excludes everything for this pixel
        // center clipped logs, reused across 8 neighbors
        float lpc[NC], lnpc[NC];
        const float* prow = prob + (size_t)pix * NC;
#pragma unroll
        for (int c = 0; c < NC; ++c) {
            const float p = prow[c];
            const float a = fminf(fmaxf(p, 1e-4f), 1.0f);
            const float b = fminf(fmaxf(1.0f - p, 1e-4f), 1.0f);
            lpc[c] = __logf(a);
            lnpc[c] = __logf(b);
        }
        const float LOGEPS = -9.210340371976182f;  // log(1e-4)

        const int DY[8] = {-1, -1, -1, 0, 0, 1, 1, 1};
        const int DX[8] = {-1, 0, 1, -1, 1, -1, 0, 1};
#pragma unroll
        for (int k = 0; k < 8; ++k) {
            const int dy = DY[k], dx = DX[k];
            // reversed-offset ignore mask (True-padded): OOB or ignored -> skip neighbor
            const int yr = y - dy, xr = x - dx;
            if ((unsigned)yr >= (unsigned)HH || (unsigned)xr >= (unsigned)WW) continue;
            if (tg[(yr << 9) + xr] > NC - 1) continue;

            const int yn = y + dy, xn = x + dx;
            if ((unsigned)yn >= (unsigned)HH || (unsigned)xn >= (unsigned)WW) {
                // neighbor OOB: one-hot pad 255 -> edge for all classes; prob pad 0
                // ppc = 1e-4 (log = LOGEPS), nppc = 1 (log = 0)
#pragma unroll
                for (int c = 0; c < NC; ++c) {
                    const float kl = 1e-4f * (LOGEPS - lpc[c]) - lnpc[c];
                    e_s += fmaxf(0.0f, 3.0f - kl);
                }
                e_c += NC;
            } else {
                const int nlab = tg[(yn << 9) + xn];
                const float* pn = prob + (size_t)((n << 18) + (yn << 9) + xn) * NC;
                // mode 0: nlab<=18 normal; mode 1: nlab==255 -> all-edge; mode 2: 19..254 -> edge iff c==lab
                const int mode = (nlab <= NC - 1) ? 0 : ((nlab == 255) ? 1 : 2);
#pragma unroll
                for (int c = 0; c < NC; ++c) {
                    const float p = pn[c];
                    const float a = fminf(fmaxf(p, 1e-4f), 1.0f);
                    const float b = fminf(fmaxf(1.0f - p, 1e-4f), 1.0f);
                    const float kl = a * (__logf(a) - lpc[c]) + b * (__logf(b) - lnpc[c]);
                    bool edge;
                    if (mode == 0)      edge = (c == lab) != (c == nlab);
                    else if (mode == 1) edge = true;
                    else                edge = (c == lab);
                    if (edge) { e_s += fmaxf(0.0f, 3.0f - kl); e_c++; }
                    else      { ne_s += kl; ne_c++; }
                }
            }
        }
        // per-pixel class weights factored out of the sums
        e_s *= swe[lab];
        ne_s *= swn[lab];
    }

    // reduction: wave(64) shuffle -> LDS -> block atomics
#pragma unroll
    for (int off = 32; off > 0; off >>= 1) {
        e_s  += __shfl_down(e_s, off, 64);
        ne_s += __shfl_down(ne_s, off, 64);
        e_c  += __shfl_down(e_c, off, 64);
        ne_c += __shfl_down(ne_c, off, 64);
    }
    __shared__ float r_es[4], r_ns[4];
    __shared__ int r_ec[4], r_nc[4];
    const int wid = tid >> 6, lane = tid & 63;
    if (lane == 0) { r_es[wid] = e_s; r_ns[wid] = ne_s; r_ec[wid] = e_c; r_nc[wid] = ne_c; }
    __syncthreads();
    if (tid == 0) {
        float tes = 0.0f, tns = 0.0f;
        int tec = 0, tnc = 0;
#pragma unroll
        for (int w = 0; w < 4; ++w) { tes += r_es[w]; tns += r_ns[w]; tec += r_ec[w]; tnc += r_nc[w]; }
        atomicAdd(&acc->e_sum, (double)tes);
        atomicAdd(&acc->ne_sum, (double)tns);
        atomicAdd(&acc->e_cnt, (unsigned long long)tec);
        atomicAdd(&acc->ne_cnt, (unsigned long long)tnc);
    }
}

// ---------------- finalize ----------------
__global__ void k_final(const Accum* acc, float* out) {
    double ec = (double)acc->e_cnt;  if (ec < 1.0) ec = 1.0;
    double nc = (double)acc->ne_cnt; if (nc < 1.0) nc = 1.0;
    const double em = acc->e_sum / ec;
    const double nem = acc->ne_sum / nc;
    out[0] = (float)(em * 0.01 + nem * 0.01);
}

extern "C" void kernel_launch(void* const* d_in, const int* in_sizes, int n_in,
                              void* d_out, int out_size, void* d_ws, size_t ws_size,
                              hipStream_t stream) {
    const float* preds      = (const float*)d_in[0];  // (2,19,64,64) fp32
    const int*   targets    = (const int*)d_in[1];    // (2,512,512) int32
    const float* w_edge     = (const float*)d_in[2];  // (1,1,1,19,1,3) fp32
    const float* w_not_edge = (const float*)d_in[3];

    float* prob = (float*)d_ws;
    Accum* acc  = (Accum*)((char*)d_ws + PROB_FLOATS * sizeof(float));

    k_init<<<1, 32, 0, stream>>>(w_edge, w_not_edge, acc);
    k_prob<<<NPIX / 256, 256, 0, stream>>>(preds, prob);
    k_main<<<NPIX / 256, 256, 0, stream>>>(targets, prob, acc);
    k_final<<<1, 1, 0, stream>>>(acc, (float*)d_out);
}

// Round 2
// 216.491 us; speedup vs baseline: 2.3686x; 2.3686x over previous
//
#include <hip/hip_runtime.h>

// AAF loss, fused single-pass tiled version.
// N=2, C=19, preds (2,19,64,64) fp32 -> bilinear(align_corners) 512x512 ->
// softmax(C) -> 8-neighbor binary-KL edge/not-edge loss -> masked means -> *0.01.
//
// Per 16x16 tile: compute softmax probs for the 18x18 halo into LDS as
// (a,b) = (clip(p), clip(1-p)) class-major float2, plus U = sum_c(a*ln a + b*ln b).
// Then sum_c kl(center, nbr) = U_nbr - sum_c(a_n*lpc_c + b_n*lnpc_c); edge classes
// (bitmask (1<<lab)^(1<<nlab), all for 255-pad) corrected exactly with recomputed kl.
// Image-OOB halo: label=255, p=0 -> (a,b)=(1e-4,1), reproducing reference padding.

#define NC 19
#define HH 512
#define WW 512
#define NB 2
#define TS 16
#define HS 18          // TS + 2 halo
#define HP (HS * HS)   // 324
#define LOGEPS -9.210340371976182f  // log(1e-4)

struct Accum {
    double e_sum, ne_sum;
    unsigned long long e_cnt, ne_cnt;
    float w_e[NC], w_ne[NC];
};

// ---------------- init: zero accumulators + class-weight softmax ----------------
__global__ void k_init(const float* __restrict__ w_edge,
                       const float* __restrict__ w_not_edge,
                       Accum* acc) {
    int t = threadIdx.x;
    if (t == 0) {
        acc->e_sum = 0.0; acc->ne_sum = 0.0;
        acc->e_cnt = 0ull; acc->ne_cnt = 0ull;
    }
    if (t < NC) {
        {
            float a = w_edge[t * 3 + 0], b = w_edge[t * 3 + 1], c = w_edge[t * 3 + 2];
            float m = fmaxf(a, fmaxf(b, c));
            float ea = __expf(a - m), eb = __expf(b - m), ec = __expf(c - m);
            acc->w_e[t] = ea / (ea + eb + ec);
        }
        {
            float a = w_not_edge[t * 3 + 0], b = w_not_edge[t * 3 + 1], c = w_not_edge[t * 3 + 2];
            float m = fmaxf(a, fmaxf(b, c));
            float ea = __expf(a - m), eb = __expf(b - m), ec = __expf(c - m);
            acc->w_ne[t] = ea / (ea + eb + ec);
        }
    }
}

// ---------------- fused tile kernel ----------------
__global__ __launch_bounds__(256) void k_fused(const float* __restrict__ preds,
                                               const int* __restrict__ targets,
                                               Accum* __restrict__ acc) {
    __shared__ float2 AB[NC][HP];   // (a,b) per class, class-major: contiguous per-wave reads
    __shared__ float  Usum[HP];     // sum_c a*ln a + b*ln b
    __shared__ int    TG[HP];       // labels incl. halo (255 for OOB)
    __shared__ float  swe[NC], swn[NC];

    const int tid = threadIdx.x;
    const int bx = blockIdx.x, by = blockIdx.y, n = blockIdx.z;

    if (tid < NC) { swe[tid] = acc->w_e[tid]; swn[tid] = acc->w_ne[tid]; }

    const int* tg = targets + (n << 18);
    const float* pb = preds + (size_t)n * NC * 4096;

    // ---- stage 1: halo softmax into LDS ----
    for (int i = tid; i < HP; i += 256) {
        const int hy = i / HS, hx = i - hy * HS;
        const int y = by * TS + hy - 1;
        const int x = bx * TS + hx - 1;
        const bool oob = ((unsigned)y >= (unsigned)HH) | ((unsigned)x >= (unsigned)WW);
        if (oob) {
            TG[i] = 255;
#pragma unroll
            for (int c = 0; c < NC; ++c) AB[c][i] = make_float2(1e-4f, 1.0f);
            // a*ln a + b*ln b = 1e-4*log(1e-4) + 0 per class
            Usum[i] = (float)NC * (1e-4f * LOGEPS);
        } else {
            TG[i] = tg[(y << 9) + x];
            // bilinear (align_corners), identical arithmetic to verified round-1
            const float fy = (float)(y * 63) / 511.0f;
            const float fx = (float)(x * 63) / 511.0f;
            const int y0 = (int)fy, x0 = (int)fx;
            const float wy = fy - (float)y0, wx = fx - (float)x0;
            const int y1 = min(y0 + 1, 63), x1 = min(x0 + 1, 63);
            const float omwy = 1.0f - wy, omwx = 1.0f - wx;

            float v[NC];
            float m = -1e30f;
#pragma unroll
            for (int c = 0; c < NC; ++c) {
                const float* pc_ = pb + c * 4096;
                const float p00 = pc_[(y0 << 6) + x0];
                const float p10 = pc_[(y1 << 6) + x0];
                const float p01 = pc_[(y0 << 6) + x1];
                const float p11 = pc_[(y1 << 6) + x1];
                const float a = p00 * omwy + p10 * wy;
                const float b = p01 * omwy + p11 * wy;
                const float vv = a * omwx + b * wx;
                v[c] = vv;
                m = fmaxf(m, vv);
            }
            float s = 0.0f;
#pragma unroll
            for (int c = 0; c < NC; ++c) { v[c] = __expf(v[c] - m); s += v[c]; }
            const float inv = 1.0f / s;
            float u = 0.0f;
#pragma unroll
            for (int c = 0; c < NC; ++c) {
                const float p = v[c] * inv;
                const float a = fminf(fmaxf(p, 1e-4f), 1.0f);
                const float b = fminf(fmaxf(1.0f - p, 1e-4f), 1.0f);
                AB[c][i] = make_float2(a, b);
                u += a * __logf(a) + b * __logf(b);
            }
            Usum[i] = u;
        }
    }
    __syncthreads();

    // ---- stage 2: per-pixel loss ----
    const int ty = tid >> 4, tx = tid & 15;
    const int hi = (ty + 1) * HS + (tx + 1);
    const int lab = TG[hi];

    float e_s = 0.0f, ne_s = 0.0f;
    int e_c = 0, ne_c = 0;

    if (lab <= NC - 1) {
        float lpc[NC], lnpc[NC];
#pragma unroll
        for (int c = 0; c < NC; ++c) {
            const float2 ab = AB[c][hi];
            lpc[c] = __logf(ab.x);
            lnpc[c] = __logf(ab.y);
        }

        const int DOFF[8] = {-HS - 1, -HS, -HS + 1, -1, 1, HS - 1, HS, HS + 1};
#pragma unroll
        for (int k = 0; k < 8; ++k) {
            const int off = DOFF[k];
            // reversed-offset ignore mask (True/255-padded): skip neighbor direction
            if (TG[hi - off] > NC - 1) continue;
            const int np = hi + off;
            const int nlab = TG[np];
            const unsigned mask = (nlab <= NC - 1) ? ((1u << lab) ^ (1u << nlab))
                                : ((nlab == 255) ? 0x7FFFFu : (1u << lab));
            float dot = 0.0f;
#pragma unroll
            for (int c = 0; c < NC; ++c) {
                const float2 ab = AB[c][np];
                dot += ab.x * lpc[c] + ab.y * lnpc[c];
            }
            float ne_k = Usum[np] - dot;   // == sum_c kl_c
            unsigned m = mask;
            while (m) {
                const int c = __ffs(m) - 1;
                m &= m - 1;
                const float2 abn = AB[c][np];
                // exact kl for this class (recompute logs; same inputs => same values)
                const float kl = abn.x * (__logf(abn.x) - __logf(AB[c][hi].x))
                               + abn.y * (__logf(abn.y) - __logf(AB[c][hi].y));
                ne_k -= kl;
                e_s += fmaxf(0.0f, 3.0f - kl);
            }
            ne_s += ne_k;
            const int pc = __popc(mask);
            e_c += pc;
            ne_c += NC - pc;
        }
        e_s *= swe[lab];
        ne_s *= swn[lab];
    }

    // ---- reduction: wave(64) shuffle -> LDS -> block atomics ----
#pragma unroll
    for (int off = 32; off > 0; off >>= 1) {
        e_s  += __shfl_down(e_s, off, 64);
        ne_s += __shfl_down(ne_s, off, 64);
        e_c  += __shfl_down(e_c, off, 64);
        ne_c += __shfl_down(ne_c, off, 64);
    }
    __shared__ float r_es[4], r_ns[4];
    __shared__ int r_ec[4], r_nc[4];
    const int wid = tid >> 6, lane = tid & 63;
    if (lane == 0) { r_es[wid] = e_s; r_ns[wid] = ne_s; r_ec[wid] = e_c; r_nc[wid] = ne_c; }
    __syncthreads();
    if (tid == 0) {
        float tes = 0.0f, tns = 0.0f;
        int tec = 0, tnc = 0;
#pragma unroll
        for (int w = 0; w < 4; ++w) { tes += r_es[w]; tns += r_ns[w]; tec += r_ec[w]; tnc += r_nc[w]; }
        atomicAdd(&acc->e_sum, (double)tes);
        atomicAdd(&acc->ne_sum, (double)tns);
        atomicAdd(&acc->e_cnt, (unsigned long long)tec);
        atomicAdd(&acc->ne_cnt, (unsigned long long)tnc);
    }
}

// ---------------- finalize ----------------
__global__ void k_final(const Accum* acc, float* out) {
    double ec = (double)acc->e_cnt;  if (ec < 1.0) ec = 1.0;
    double nc = (double)acc->ne_cnt; if (nc < 1.0) nc = 1.0;
    out[0] = (float)((acc->e_sum / ec) * 0.01 + (acc->ne_sum / nc) * 0.01);
}

extern "C" void kernel_launch(void* const* d_in, const int* in_sizes, int n_in,
                              void* d_out, int out_size, void* d_ws, size_t ws_size,
                              hipStream_t stream) {
    const float* preds      = (const float*)d_in[0];  // (2,19,64,64) fp32
    const int*   targets    = (const int*)d_in[1];    // (2,512,512) int32
    const float* w_edge     = (const float*)d_in[2];  // (1,1,1,19,1,3) fp32
    const float* w_not_edge = (const float*)d_in[3];

    Accum* acc = (Accum*)d_ws;

    k_init<<<1, 32, 0, stream>>>(w_edge, w_not_edge, acc);
    dim3 grid(WW / TS, HH / TS, NB);
    k_fused<<<grid, 256, 0, stream>>>(preds, targets, acc);
    k_final<<<1, 1, 0, stream>>>(acc, (float*)d_out);
}

// Round 3
// 172.204 us; speedup vs baseline: 2.9777x; 1.2572x over previous
//
#include <hip/hip_runtime.h>

// AAF loss, fused single-pass tiled version, round 3.
// Changes vs R2: pixel-major prob-only LDS (27 KB, stride-19 rows -> conflict-free,
// 5 blocks/CU), per-block class-weight softmax (drops k_init), per-block partial
// array + tree-reduce final kernel (drops atomics + init), 2 launches total.

#define NC 19
#define HH 512
#define WW 512
#define NB 2
#define TS 16
#define HS 18                         // TS + 2 halo
#define HP (HS * HS)                  // 324
#define NBLK (NB * (HH / TS) * (WW / TS))  // 2048
#define LOGEPS -9.210340371976182f    // log(1e-4)

struct Part { float es, ns; int ec, nc; };

// ---------------- fused tile kernel ----------------
__global__ __launch_bounds__(256) void k_fused(const float* __restrict__ preds,
                                               const int* __restrict__ targets,
                                               const float* __restrict__ w_edge,
                                               const float* __restrict__ w_not_edge,
                                               Part* __restrict__ pb) {
    __shared__ float P[HP * NC];   // softmax probs, pixel-major (stride 19 words)
    __shared__ float Usum[HP];     // sum_c a*ln a + b*ln b
    __shared__ int   TG[HP];       // labels incl. halo (255 for image-OOB)
    __shared__ float swe[NC], swn[NC];

    const int tid = threadIdx.x;
    const int bx = blockIdx.x, by = blockIdx.y, n = blockIdx.z;

    // per-block class-weight softmax (19 threads, replaces k_init)
    if (tid < NC) {
        {
            float a = w_edge[tid * 3 + 0], b = w_edge[tid * 3 + 1], c = w_edge[tid * 3 + 2];
            float m = fmaxf(a, fmaxf(b, c));
            float ea = __expf(a - m), eb = __expf(b - m), ec = __expf(c - m);
            swe[tid] = ea / (ea + eb + ec);
        }
        {
            float a = w_not_edge[tid * 3 + 0], b = w_not_edge[tid * 3 + 1], c = w_not_edge[tid * 3 + 2];
            float m = fmaxf(a, fmaxf(b, c));
            float ea = __expf(a - m), eb = __expf(b - m), ec = __expf(c - m);
            swn[tid] = ea / (ea + eb + ec);
        }
    }

    const int* tg = targets + (n << 18);
    const float* pbase = preds + (size_t)n * NC * 4096;

    // ---- stage 1: halo softmax into LDS ----
    for (int i = tid; i < HP; i += 256) {
        const int hy = i / HS, hx = i - hy * HS;
        const int y = by * TS + hy - 1;
        const int x = bx * TS + hx - 1;
        float* Prow = &P[i * NC];
        if (((unsigned)y >= (unsigned)HH) | ((unsigned)x >= (unsigned)WW)) {
            TG[i] = 255;
#pragma unroll
            for (int c = 0; c < NC; ++c) Prow[c] = 0.0f;   // pad prob 0 -> (a,b)=(1e-4,1)
            Usum[i] = (float)NC * (1e-4f * LOGEPS);
        } else {
            TG[i] = tg[(y << 9) + x];
            // bilinear align_corners 512 -> 64
            const float fy = (float)(y * 63) / 511.0f;
            const float fx = (float)(x * 63) / 511.0f;
            const int y0 = (int)fy, x0 = (int)fx;
            const float wy = fy - (float)y0, wx = fx - (float)x0;
            const int y1 = min(y0 + 1, 63), x1 = min(x0 + 1, 63);
            const float omwy = 1.0f - wy, omwx = 1.0f - wx;

            float v[NC];
            float m = -1e30f;
#pragma unroll
            for (int c = 0; c < NC; ++c) {
                const float* pc_ = pbase + c * 4096;
                const float p00 = pc_[(y0 << 6) + x0];
                const float p10 = pc_[(y1 << 6) + x0];
                const float p01 = pc_[(y0 << 6) + x1];
                const float p11 = pc_[(y1 << 6) + x1];
                const float a = p00 * omwy + p10 * wy;
                const float b = p01 * omwy + p11 * wy;
                const float vv = a * omwx + b * wx;
                v[c] = vv;
                m = fmaxf(m, vv);
            }
            float s = 0.0f;
#pragma unroll
            for (int c = 0; c < NC; ++c) { v[c] = __expf(v[c] - m); s += v[c]; }
            const float inv = 1.0f / s;
            float u = 0.0f;
#pragma unroll
            for (int c = 0; c < NC; ++c) {
                const float p = v[c] * inv;
                Prow[c] = p;
                const float a = fmaxf(p, 1e-4f);
                const float b = fmaxf(1.0f - p, 1e-4f);
                u += a * __logf(a) + b * __logf(b);
            }
            Usum[i] = u;
        }
    }
    __syncthreads();

    // ---- stage 2: per-pixel loss ----
    const int ty = tid >> 4, tx = tid & 15;
    const int hi = (ty + 1) * HS + (tx + 1);
    const int lab = TG[hi];

    float e_s = 0.0f, ne_s = 0.0f;
    int e_c = 0, ne_c = 0;

    if (lab <= NC - 1) {
        const float* Ph = &P[hi * NC];
        float lpc[NC], lnpc[NC];    // static-index only (unrolled) -> stays in VGPRs
#pragma unroll
        for (int c = 0; c < NC; ++c) {
            const float p = Ph[c];
            lpc[c]  = __logf(fmaxf(p, 1e-4f));
            lnpc[c] = __logf(fmaxf(1.0f - p, 1e-4f));
        }

        const int DOFF[8] = {-HS - 1, -HS, -HS + 1, -1, 1, HS - 1, HS, HS + 1};
#pragma unroll
        for (int k = 0; k < 8; ++k) {
            const int off = DOFF[k];
            if (TG[hi - off] > NC - 1) continue;   // reversed-offset ignore (255-padded)
            const int np = hi + off;
            const int nlab = TG[np];
            const unsigned mask = (nlab <= NC - 1) ? ((1u << lab) ^ (1u << nlab))
                                : ((nlab == 255) ? 0x7FFFFu : (1u << lab));
            const float* Pn = &P[np * NC];
            float dot = 0.0f;
#pragma unroll
            for (int c = 0; c < NC; ++c) {
                const float p = Pn[c];
                const float a = fmaxf(p, 1e-4f);
                const float b = fmaxf(1.0f - p, 1e-4f);
                dot += a * lpc[c] + b * lnpc[c];
            }
            float ne_k = Usum[np] - dot;           // == sum_c kl_c
            unsigned m = mask;
            while (m) {
                const int c = __ffs(m) - 1;
                m &= m - 1;
                // dynamic class index -> read from LDS (not register arrays)
                const float pn = Pn[c];
                const float an = fmaxf(pn, 1e-4f);
                const float bn = fmaxf(1.0f - pn, 1e-4f);
                const float ph = Ph[c];
                const float ah = fmaxf(ph, 1e-4f);
                const float bh = fmaxf(1.0f - ph, 1e-4f);
                const float kl = an * (__logf(an) - __logf(ah))
                               + bn * (__logf(bn) - __logf(bh));
                ne_k -= kl;
                e_s += fmaxf(0.0f, 3.0f - kl);
            }
            ne_s += ne_k;
            const int pc = __popc(mask);
            e_c += pc;
            ne_c += NC - pc;
        }
        e_s *= swe[lab];
        ne_s *= swn[lab];
    }

    // ---- block reduction: wave(64) shuffle -> LDS -> one Part per block ----
#pragma unroll
    for (int off = 32; off > 0; off >>= 1) {
        e_s  += __shfl_down(e_s, off, 64);
        ne_s += __shfl_down(ne_s, off, 64);
        e_c  += __shfl_down(e_c, off, 64);
        ne_c += __shfl_down(ne_c, off, 64);
    }
    __shared__ float r_es[4], r_ns[4];
    __shared__ int r_ec[4], r_nc[4];
    const int wid = tid >> 6, lane = tid & 63;
    if (lane == 0) { r_es[wid] = e_s; r_ns[wid] = ne_s; r_ec[wid] = e_c; r_nc[wid] = ne_c; }
    __syncthreads();
    if (tid == 0) {
        float tes = 0.0f, tns = 0.0f;
        int tec = 0, tnc = 0;
#pragma unroll
        for (int w = 0; w < 4; ++w) { tes += r_es[w]; tns += r_ns[w]; tec += r_ec[w]; tnc += r_nc[w]; }
        const int bid = (blockIdx.z * gridDim.y + blockIdx.y) * gridDim.x + blockIdx.x;
        pb[bid].es = tes; pb[bid].ns = tns; pb[bid].ec = tec; pb[bid].nc = tnc;
    }
}

// ---------------- final reduce (1 block) ----------------
__global__ __launch_bounds__(256) void k_final(const Part* __restrict__ pb,
                                               float* __restrict__ out) {
    const int tid = threadIdx.x;
    double es = 0.0, ns = 0.0;
    long long ec = 0, nc = 0;
    for (int i = tid; i < NBLK; i += 256) {
        es += (double)pb[i].es; ns += (double)pb[i].ns;
        ec += pb[i].ec; nc += pb[i].nc;
    }
#pragma unroll
    for (int off = 32; off > 0; off >>= 1) {
        es += __shfl_down(es, off, 64);
        ns += __shfl_down(ns, off, 64);
        ec += __shfl_down(ec, off, 64);
        nc += __shfl_down(nc, off, 64);
    }
    __shared__ double ses[4], sns[4];
    __shared__ long long sec[4], snc[4];
    const int wid = tid >> 6, lane = tid & 63;
    if (lane == 0) { ses[wid] = es; sns[wid] = ns; sec[wid] = ec; snc[wid] = nc; }
    __syncthreads();
    if (tid == 0) {
        double tes = 0.0, tns = 0.0;
        long long tec = 0, tnc = 0;
#pragma unroll
        for (int w = 0; w < 4; ++w) { tes += ses[w]; tns += sns[w]; tec += sec[w]; tnc += snc[w]; }
        double ecd = (double)tec; if (ecd < 1.0) ecd = 1.0;
        double ncd = (double)tnc; if (ncd < 1.0) ncd = 1.0;
        out[0] = (float)((tes / ecd) * 0.01 + (tns / ncd) * 0.01);
    }
}

extern "C" void kernel_launch(void* const* d_in, const int* in_sizes, int n_in,
                              void* d_out, int out_size, void* d_ws, size_t ws_size,
                              hipStream_t stream) {
    const float* preds      = (const float*)d_in[0];  // (2,19,64,64) fp32
    const int*   targets    = (const int*)d_in[1];    // (2,512,512) int32
    const float* w_edge     = (const float*)d_in[2];  // (1,1,1,19,1,3) fp32
    const float* w_not_edge = (const float*)d_in[3];

    Part* pb = (Part*)d_ws;   // 2048 * 16 B; every slot written by k_fused

    dim3 grid(WW / TS, HH / TS, NB);
    k_fused<<<grid, 256, 0, stream>>>(preds, targets, w_edge, w_not_edge, pb);
    k_final<<<1, 256, 0, stream>>>(pb, (float*)d_out);
}

// Round 4
// 108.296 us; speedup vs baseline: 4.7349x; 1.5901x over previous
//
#include <hip/hip_runtime.h>

// AAF loss, fused tiled version, round 4: branchless straight-line stage 2.
// LDS per (halo pixel, class): float2 (a, t), a = clip(p), t = a*ln a + b*ln b.
// kl_c = t_n - fma(a_n, d_h[c], lb_h[c]) with d = la - lb (b ~ 1-a); edge routing
// via per-class mask bit as a float multiplier; reverse-ignore via per-neighbor
// 0/1 weight. No logf, no branches, no while-loop in the neighbor loops.

#define NC 19
#define HH 512
#define WW 512
#define NB 2
#define TS 16
#define HS 18                         // TS + 2 halo
#define HP (HS * HS)                  // 324
#define NBLK (NB * (HH / TS) * (WW / TS))  // 2048
#define LOGEPS -9.210340371976182f    // log(1e-4)

struct Part { float es, ns; int ec, nc; };

__global__ __launch_bounds__(256, 3) void k_fused(const float* __restrict__ preds,
                                                  const int* __restrict__ targets,
                                                  const float* __restrict__ w_edge,
                                                  const float* __restrict__ w_not_edge,
                                                  Part* __restrict__ pb) {
    __shared__ float2 AT[HP * NC];  // (a, t) pixel-major, row stride 19*8 B (8B aligned)
    __shared__ int    TG[HP];       // labels incl. halo (255 for image-OOB)
    __shared__ float  swe[NC], swn[NC];

    const int tid = threadIdx.x;
    const int bx = blockIdx.x, by = blockIdx.y, n = blockIdx.z;

    // per-block class-weight softmax
    if (tid < NC) {
        {
            float a = w_edge[tid * 3 + 0], b = w_edge[tid * 3 + 1], c = w_edge[tid * 3 + 2];
            float m = fmaxf(a, fmaxf(b, c));
            float ea = __expf(a - m), eb = __expf(b - m), ec = __expf(c - m);
            swe[tid] = ea / (ea + eb + ec);
        }
        {
            float a = w_not_edge[tid * 3 + 0], b = w_not_edge[tid * 3 + 1], c = w_not_edge[tid * 3 + 2];
            float m = fmaxf(a, fmaxf(b, c));
            float ea = __expf(a - m), eb = __expf(b - m), ec = __expf(c - m);
            swn[tid] = ea / (ea + eb + ec);
        }
    }

    const int* tg = targets + (n << 18);
    const float* pbase = preds + (size_t)n * NC * 4096;

    // ---- stage 1: halo softmax -> (a, t) into LDS ----
    for (int i = tid; i < HP; i += 256) {
        const int hy = i / HS, hx = i - hy * HS;
        const int y = by * TS + hy - 1;
        const int x = bx * TS + hx - 1;
        float2* Arow = &AT[i * NC];
        if (((unsigned)y >= (unsigned)HH) | ((unsigned)x >= (unsigned)WW)) {
            TG[i] = 255;
#pragma unroll
            for (int c = 0; c < NC; ++c) Arow[c] = make_float2(1e-4f, 1e-4f * LOGEPS);
        } else {
            TG[i] = tg[(y << 9) + x];
            const float fy = (float)(y * 63) / 511.0f;
            const float fx = (float)(x * 63) / 511.0f;
            const int y0 = (int)fy, x0 = (int)fx;
            const float wy = fy - (float)y0, wx = fx - (float)x0;
            const int y1 = min(y0 + 1, 63), x1 = min(x0 + 1, 63);
            const float omwy = 1.0f - wy, omwx = 1.0f - wx;

            float v[NC];
            float m = -1e30f;
#pragma unroll
            for (int c = 0; c < NC; ++c) {
                const float* pc_ = pbase + c * 4096;
                const float p00 = pc_[(y0 << 6) + x0];
                const float p10 = pc_[(y1 << 6) + x0];
                const float p01 = pc_[(y0 << 6) + x1];
                const float p11 = pc_[(y1 << 6) + x1];
                const float a = p00 * omwy + p10 * wy;
                const float b = p01 * omwy + p11 * wy;
                const float vv = a * omwx + b * wx;
                v[c] = vv;
                m = fmaxf(m, vv);
            }
            float s = 0.0f;
#pragma unroll
            for (int c = 0; c < NC; ++c) { v[c] = __expf(v[c] - m); s += v[c]; }
            const float inv = 1.0f / s;
#pragma unroll
            for (int c = 0; c < NC; ++c) {
                const float p = v[c] * inv;
                const float a = fmaxf(p, 1e-4f);
                const float b = fmaxf(1.0f - p, 1e-4f);
                const float t = a * __logf(a) + b * __logf(b);
                Arow[c] = make_float2(a, t);
            }
        }
    }
    __syncthreads();

    // ---- stage 2: branchless per-pixel loss ----
    const int ty = tid >> 4, tx = tid & 15;
    const int hi = (ty + 1) * HS + (tx + 1);
    const int lab = TG[hi];

    float e_s = 0.0f, ne_s = 0.0f;
    int e_c = 0, ne_c = 0;

    if (lab <= NC - 1) {   // always true in-dataset; exec-masked, no serialization
        const float2* Ah = &AT[hi * NC];
        float dd[NC], lbh[NC];   // d = la - lb, lb (center), static-index -> VGPRs
#pragma unroll
        for (int c = 0; c < NC; ++c) {
            const float a = Ah[c].x;
            const float la = __logf(a);
            const float lb = __logf(fmaxf(1.0f - a, 1e-4f));
            dd[c] = la - lb;
            lbh[c] = lb;
        }

        const unsigned mlab = 1u << lab;
        const int DOFF[8] = {-HS - 1, -HS, -HS + 1, -1, 1, HS - 1, HS, HS + 1};
#pragma unroll
        for (int k = 0; k < 8; ++k) {
            const int off = DOFF[k];
            const int rlab = TG[hi - off];              // reversed-offset ignore source
            const int nlab = TG[hi + off];
            const bool valid = (rlab <= NC - 1);
            const unsigned mask = (nlab <= NC - 1) ? (mlab ^ (1u << nlab))
                                : ((nlab == 255) ? 0x7FFFFu : mlab);
            const float2* An = &AT[(hi + off) * NC];
            float ek = 0.0f, nk = 0.0f;
#pragma unroll
            for (int c = 0; c < NC; ++c) {
                const float2 at = An[c];                // ds_read_b64, imm offset
                const float x = fmaf(at.x, dd[c], lbh[c]);   // a*la_h + (1-a)*lb_h
                const float kl = at.y - x;
                const float ef = (float)((mask >> c) & 1u);
                ek = fmaf(ef, fmaxf(3.0f - kl, 0.0f), ek);
                nk = fmaf(1.0f - ef, kl, nk);
            }
            const float vf = valid ? 1.0f : 0.0f;
            e_s = fmaf(vf, ek, e_s);
            ne_s = fmaf(vf, nk, ne_s);
            const int pc = __popc(mask);
            e_c += valid ? pc : 0;
            ne_c += valid ? (NC - pc) : 0;
        }
        e_s *= swe[lab];
        ne_s *= swn[lab];
    }

    // ---- block reduction: wave(64) shuffle -> LDS -> one Part per block ----
#pragma unroll
    for (int off = 32; off > 0; off >>= 1) {
        e_s  += __shfl_down(e_s, off, 64);
        ne_s += __shfl_down(ne_s, off, 64);
        e_c  += __shfl_down(e_c, off, 64);
        ne_c += __shfl_down(ne_c, off, 64);
    }
    __shared__ float r_es[4], r_ns[4];
    __shared__ int r_ec[4], r_nc[4];
    const int wid = tid >> 6, lane = tid & 63;
    if (lane == 0) { r_es[wid] = e_s; r_ns[wid] = ne_s; r_ec[wid] = e_c; r_nc[wid] = ne_c; }
    __syncthreads();
    if (tid == 0) {
        float tes = 0.0f, tns = 0.0f;
        int tec = 0, tnc = 0;
#pragma unroll
        for (int w = 0; w < 4; ++w) { tes += r_es[w]; tns += r_ns[w]; tec += r_ec[w]; tnc += r_nc[w]; }
        const int bid = (blockIdx.z * gridDim.y + blockIdx.y) * gridDim.x + blockIdx.x;
        pb[bid].es = tes; pb[bid].ns = tns; pb[bid].ec = tec; pb[bid].nc = tnc;
    }
}

// ---------------- final reduce (1 block) ----------------
__global__ __launch_bounds__(256) void k_final(const Part* __restrict__ pb,
                                               float* __restrict__ out) {
    const int tid = threadIdx.x;
    double es = 0.0, ns = 0.0;
    long long ec = 0, nc = 0;
    for (int i = tid; i < NBLK; i += 256) {
        es += (double)pb[i].es; ns += (double)pb[i].ns;
        ec += pb[i].ec; nc += pb[i].nc;
    }
#pragma unroll
    for (int off = 32; off > 0; off >>= 1) {
        es += __shfl_down(es, off, 64);
        ns += __shfl_down(ns, off, 64);
        ec += __shfl_down(ec, off, 64);
        nc += __shfl_down(nc, off, 64);
    }
    __shared__ double ses[4], sns[4];
    __shared__ long long sec[4], snc[4];
    const int wid = tid >> 6, lane = tid & 63;
    if (lane == 0) { ses[wid] = es; sns[wid] = ns; sec[wid] = ec; snc[wid] = nc; }
    __syncthreads();
    if (tid == 0) {
        double tes = 0.0, tns = 0.0;
        long long tec = 0, tnc = 0;
#pragma unroll
        for (int w = 0; w < 4; ++w) { tes += ses[w]; tns += sns[w]; tec += sec[w]; tnc += snc[w]; }
        double ecd = (double)tec; if (ecd < 1.0) ecd = 1.0;
        double ncd = (double)tnc; if (ncd < 1.0) ncd = 1.0;
        out[0] = (float)((tes / ecd) * 0.01 + (tns / ncd) * 0.01);
    }
}

extern "C" void kernel_launch(void* const* d_in, const int* in_sizes, int n_in,
                              void* d_out, int out_size, void* d_ws, size_t ws_size,
                              hipStream_t stream) {
    const float* preds      = (const float*)d_in[0];  // (2,19,64,64) fp32
    const int*   targets    = (const int*)d_in[1];    // (2,512,512) int32
    const float* w_edge     = (const float*)d_in[2];  // (1,1,1,19,1,3) fp32
    const float* w_not_edge = (const float*)d_in[3];

    Part* pb = (Part*)d_ws;   // 2048 * 16 B; every slot written by k_fused

    dim3 grid(WW / TS, HH / TS, NB);
    k_fused<<<grid, 256, 0, stream>>>(preds, targets, w_edge, w_not_edge, pb);
    k_final<<<1, 256, 0, stream>>>(pb, (float*)d_out);
}